// Round 1
// baseline (524.159 us; speedup 1.0000x reference)
//
#include <hip/hip_runtime.h>
#include <stdint.h>

#define BATCH 4
#define SEQ 2048
#define DMODEL 1024
#define NHEADS 16
#define HDIM 64
#define MROWS (BATCH * SEQ)   // 8192

typedef float floatx4 __attribute__((ext_vector_type(4)));
typedef __bf16 bf16x8 __attribute__((ext_vector_type(8)));

__device__ __forceinline__ unsigned short f32_to_bf16(float f) {
    union { float f; unsigned int u; } c; c.f = f;
    unsigned int u = c.u;
    unsigned int r = (u + 0x7FFFu + ((u >> 16) & 1u)) >> 16;
    return (unsigned short)r;
}

// ---------------------------------------------------------------- convert x
__global__ __launch_bounds__(256) void conv_f32_bf16(
    const float* __restrict__ in, unsigned short* __restrict__ out, int n4) {
    int i = blockIdx.x * 256 + threadIdx.x;
    if (i < n4) {
        float4 v = ((const float4*)in)[i];
        ushort4 o;
        o.x = f32_to_bf16(v.x); o.y = f32_to_bf16(v.y);
        o.z = f32_to_bf16(v.z); o.w = f32_to_bf16(v.w);
        ((ushort4*)out)[i] = o;
    }
}

// ------------------------------------------- transpose+convert W [K,N] -> [N,K] bf16
__global__ __launch_bounds__(256) void transp_conv(
    const float* __restrict__ in, unsigned short* __restrict__ out, int K, int N) {
    __shared__ float tile[32][33];
    int bx = blockIdx.x * 32;  // n
    int by = blockIdx.y * 32;  // k
    int tx = threadIdx.x, ty = threadIdx.y;
#pragma unroll
    for (int i = 0; i < 4; ++i)
        tile[ty + i * 8][tx] = in[(size_t)(by + ty + i * 8) * N + bx + tx];
    __syncthreads();
#pragma unroll
    for (int i = 0; i < 4; ++i)
        out[(size_t)(bx + ty + i * 8) * K + by + tx] = f32_to_bf16(tile[tx][ty + i * 8]);
}

// ------------------------------------- per-head bf16 transpose [T,64] -> [64,T]
__global__ __launch_bounds__(256) void transp_bf16_head(
    const unsigned short* __restrict__ in, unsigned short* __restrict__ out) {
    __shared__ unsigned short tile[32][33];
    const unsigned short* src = in + (size_t)blockIdx.z * SEQ * HDIM;
    unsigned short* dst = out + (size_t)blockIdx.z * SEQ * HDIM;
    int bx = blockIdx.x * 32;  // d block
    int by = blockIdx.y * 32;  // t block
    int tx = threadIdx.x, ty = threadIdx.y;
#pragma unroll
    for (int i = 0; i < 4; ++i)
        tile[ty + i * 8][tx] = src[(size_t)(by + ty + i * 8) * HDIM + bx + tx];
    __syncthreads();
#pragma unroll
    for (int i = 0; i < 4; ++i)
        dst[(size_t)(bx + ty + i * 8) * SEQ + by + tx] = tile[tx][ty + i * 8];
}

// ---------------------------------------------------------------- GEMM (B^T input)
// C[M,N] = A[M,K] * B[K,N] + bias ; Bt is [N,K] bf16.
// EPI=0: scatter to Q/K/V [B,H,T,D] bf16. EPI=1: write f32 to Cout.
template <int EPI>
__global__ __launch_bounds__(256) void gemm_bt(
    const unsigned short* __restrict__ A, const unsigned short* __restrict__ Bt,
    const float* __restrict__ bias, float* __restrict__ Cout,
    unsigned short* __restrict__ Qo, unsigned short* __restrict__ Ko,
    unsigned short* __restrict__ Vo, int M, int N, int K) {
    __shared__ __align__(16) unsigned short As[128 * 32];
    __shared__ __align__(16) unsigned short Bs[128 * 32];
    const int tid = threadIdx.x;
    const int lane = tid & 63;
    const int w = tid >> 6;
    const int wm = w & 1, wn = w >> 1;
    const int quad = lane >> 4, l16 = lane & 15;
    const int m0 = blockIdx.y * 128;
    const int n0 = blockIdx.x * 128;

    floatx4 acc[4][4];
#pragma unroll
    for (int mt = 0; mt < 4; ++mt)
#pragma unroll
        for (int nt = 0; nt < 4; ++nt) acc[mt][nt] = (floatx4){0.f, 0.f, 0.f, 0.f};

    for (int k0 = 0; k0 < K; k0 += 32) {
#pragma unroll
        for (int r = 0; r < 2; ++r) {
            int idx = tid + r * 256;
            int row = idx >> 2, ch = (idx & 3) * 8;
            *(uint4*)&As[row * 32 + ch] = *(const uint4*)&A[(size_t)(m0 + row) * K + k0 + ch];
            *(uint4*)&Bs[row * 32 + ch] = *(const uint4*)&Bt[(size_t)(n0 + row) * K + k0 + ch];
        }
        __syncthreads();
        bf16x8 aF[4], bF[4];
#pragma unroll
        for (int mt = 0; mt < 4; ++mt)
            aF[mt] = *(const bf16x8*)&As[(wm * 64 + mt * 16 + l16) * 32 + quad * 8];
#pragma unroll
        for (int nt = 0; nt < 4; ++nt)
            bF[nt] = *(const bf16x8*)&Bs[(wn * 64 + nt * 16 + l16) * 32 + quad * 8];
#pragma unroll
        for (int mt = 0; mt < 4; ++mt)
#pragma unroll
            for (int nt = 0; nt < 4; ++nt)
                acc[mt][nt] = __builtin_amdgcn_mfma_f32_16x16x32_bf16(
                    aF[mt], bF[nt], acc[mt][nt], 0, 0, 0);
        __syncthreads();
    }

#pragma unroll
    for (int mt = 0; mt < 4; ++mt)
#pragma unroll
        for (int nt = 0; nt < 4; ++nt)
#pragma unroll
            for (int r = 0; r < 4; ++r) {
                int m = m0 + wm * 64 + mt * 16 + quad * 4 + r;
                int n = n0 + wn * 64 + nt * 16 + l16;
                float v = acc[mt][nt][r] + bias[n];
                if (EPI == 1) {
                    Cout[(size_t)m * N + n] = v;
                } else {
                    int sel = n >> 10, c = n & 1023;
                    int head = c >> 6, d = c & 63;
                    int bb = m >> 11, t = m & 2047;
                    unsigned short* dst = sel == 0 ? Qo : (sel == 1 ? Ko : Vo);
                    dst[((((size_t)bb * NHEADS + head) * SEQ + t) << 6) + d] = f32_to_bf16(v);
                }
            }
}

// ---------------------------------------------------------------- flash attention
// grid: (T/64, B*H); block 256 (4 waves). Q,K: [B,H,T,D]; Vt: [B,H,D,T]; Yatt: [B,T,C] bf16
__global__ __launch_bounds__(256) void attn_kernel(
    const unsigned short* __restrict__ Qg, const unsigned short* __restrict__ Kg,
    const unsigned short* __restrict__ Vtg, unsigned short* __restrict__ Yatt) {
    __shared__ __align__(16) unsigned short Qs[64 * 64];
    __shared__ __align__(16) unsigned short Ks[64 * 64];
    __shared__ __align__(16) unsigned short VsT[64 * 64];  // [d][key]
    __shared__ __align__(16) unsigned short Ps[4][16 * 64];

    const int tid = threadIdx.x;
    const int lane = tid & 63;
    const int w = tid >> 6;
    const int quad = lane >> 4, l16 = lane & 15;
    const int qb = blockIdx.x;
    const int bh = blockIdx.y;
    const size_t base = (size_t)bh * SEQ * HDIM;

#pragma unroll
    for (int r = 0; r < 2; ++r) {
        int idx = tid + r * 256;
        int row = idx >> 3, ch = (idx & 7) * 8;
        *(uint4*)&Qs[row * 64 + ch] = *(const uint4*)&Qg[base + (size_t)(qb * 64 + row) * 64 + ch];
    }

    float mI[4] = {-INFINITY, -INFINITY, -INFINITY, -INFINITY};
    float lI[4] = {0.f, 0.f, 0.f, 0.f};
    floatx4 o[4];
#pragma unroll
    for (int nt = 0; nt < 4; ++nt) o[nt] = (floatx4){0.f, 0.f, 0.f, 0.f};

    for (int kb = 0; kb <= qb; ++kb) {
        __syncthreads();  // protect Ks/VsT from previous iteration's readers
#pragma unroll
        for (int r = 0; r < 2; ++r) {
            int idx = tid + r * 256;
            int row = idx >> 3, ch = (idx & 7) * 8;
            *(uint4*)&Ks[row * 64 + ch] =
                *(const uint4*)&Kg[base + (size_t)(kb * 64 + row) * 64 + ch];
            *(uint4*)&VsT[row * 64 + ch] =
                *(const uint4*)&Vtg[base + (size_t)row * SEQ + kb * 64 + ch];
        }
        __syncthreads();

        // S = Q * K^T  (A: m=lane&15 rows of wave tile, B from K rows)
        floatx4 s[4];
#pragma unroll
        for (int nt = 0; nt < 4; ++nt) s[nt] = (floatx4){0.f, 0.f, 0.f, 0.f};
#pragma unroll
        for (int kk = 0; kk < 2; ++kk) {
            bf16x8 a = *(const bf16x8*)&Qs[(w * 16 + l16) * 64 + kk * 32 + quad * 8];
#pragma unroll
            for (int nt = 0; nt < 4; ++nt) {
                bf16x8 bfr = *(const bf16x8*)&Ks[(nt * 16 + l16) * 64 + kk * 32 + quad * 8];
                s[nt] = __builtin_amdgcn_mfma_f32_16x16x32_bf16(a, bfr, s[nt], 0, 0, 0);
            }
        }
        const bool diag = (kb == qb);
#pragma unroll
        for (int nt = 0; nt < 4; ++nt)
#pragma unroll
            for (int r = 0; r < 4; ++r) {
                float sv = s[nt][r] * 0.125f;
                if (diag && (nt * 16 + l16) > (w * 16 + quad * 4 + r)) sv = -INFINITY;
                s[nt][r] = sv;
            }
        // online softmax per row (row = quad*4 + r; row lives in the quad's 16 lanes)
#pragma unroll
        for (int r = 0; r < 4; ++r) {
            float rm = fmaxf(fmaxf(s[0][r], s[1][r]), fmaxf(s[2][r], s[3][r]));
            rm = fmaxf(rm, __shfl_xor(rm, 1, 16));
            rm = fmaxf(rm, __shfl_xor(rm, 2, 16));
            rm = fmaxf(rm, __shfl_xor(rm, 4, 16));
            rm = fmaxf(rm, __shfl_xor(rm, 8, 16));
            float mNew = fmaxf(mI[r], rm);
            float alpha = __expf(mI[r] - mNew);
            mI[r] = mNew;
            float rs = 0.f;
#pragma unroll
            for (int nt = 0; nt < 4; ++nt) {
                float p = __expf(s[nt][r] - mNew);
                s[nt][r] = p;
                rs += p;
            }
            rs += __shfl_xor(rs, 1, 16);
            rs += __shfl_xor(rs, 2, 16);
            rs += __shfl_xor(rs, 4, 16);
            rs += __shfl_xor(rs, 8, 16);
            lI[r] = lI[r] * alpha + rs;
#pragma unroll
            for (int nt = 0; nt < 4; ++nt) o[nt][r] *= alpha;
        }
        // P: C/D layout -> LDS -> A layout
#pragma unroll
        for (int nt = 0; nt < 4; ++nt)
#pragma unroll
            for (int r = 0; r < 4; ++r)
                Ps[w][(quad * 4 + r) * 64 + nt * 16 + l16] = f32_to_bf16(s[nt][r]);
        __syncthreads();
        // O += P * V   (B operand from VsT[d][key], contiguous)
#pragma unroll
        for (int kk = 0; kk < 2; ++kk) {
            bf16x8 a = *(const bf16x8*)&Ps[w][l16 * 64 + kk * 32 + quad * 8];
#pragma unroll
            for (int nt = 0; nt < 4; ++nt) {
                bf16x8 bfr = *(const bf16x8*)&VsT[(nt * 16 + l16) * 64 + kk * 32 + quad * 8];
                o[nt] = __builtin_amdgcn_mfma_f32_16x16x32_bf16(a, bfr, o[nt], 0, 0, 0);
            }
        }
    }

    const int bIdx = bh >> 4, h = bh & 15;
#pragma unroll
    for (int nt = 0; nt < 4; ++nt)
#pragma unroll
        for (int r = 0; r < 4; ++r) {
            int qrow = qb * 64 + w * 16 + quad * 4 + r;
            int col = h * 64 + nt * 16 + l16;
            float val = o[nt][r] / lI[r];
            Yatt[((size_t)(bIdx * SEQ + qrow) << 10) + col] = f32_to_bf16(val);
        }
}

// ---------------------------------------------------------------- launch
extern "C" void kernel_launch(void* const* d_in, const int* in_sizes, int n_in,
                              void* d_out, int out_size, void* d_ws, size_t ws_size,
                              hipStream_t stream) {
    const float* x = (const float*)d_in[0];
    const float* w_qkv = (const float*)d_in[1];
    const float* b_qkv = (const float*)d_in[2];
    const float* w_proj = (const float*)d_in[3];
    const float* b_proj = (const float*)d_in[4];
    float* out = (float*)d_out;

    char* ws = (char*)d_ws;
    // byte offsets (all 256-aligned); total ~104 MB
    unsigned short* xb     = (unsigned short*)(ws);                       // 16 MB
    unsigned short* wqkvT  = (unsigned short*)(ws + 16777216);            // 6 MB
    unsigned short* wprojT = (unsigned short*)(ws + 23068672);            // 2 MB
    unsigned short* Qb     = (unsigned short*)(ws + 25165824);            // 16 MB
    unsigned short* Kb     = (unsigned short*)(ws + 41943040);            // 16 MB
    unsigned short* Vb     = (unsigned short*)(ws + 58720256);            // 16 MB
    unsigned short* Yatt   = (unsigned short*)(ws + 75497472);            // 16 MB
    unsigned short* Vt     = (unsigned short*)(ws + 92274688);            // 16 MB

    conv_f32_bf16<<<8192, 256, 0, stream>>>(x, xb, (MROWS * DMODEL) / 4);
    transp_conv<<<dim3(96, 32), dim3(32, 8), 0, stream>>>(w_qkv, wqkvT, DMODEL, 3 * DMODEL);
    transp_conv<<<dim3(32, 32), dim3(32, 8), 0, stream>>>(w_proj, wprojT, DMODEL, DMODEL);
    gemm_bt<0><<<dim3(24, 64), 256, 0, stream>>>(xb, wqkvT, b_qkv, nullptr, Qb, Kb, Vb,
                                                 MROWS, 3 * DMODEL, DMODEL);
    transp_bf16_head<<<dim3(2, 64, BATCH * NHEADS), dim3(32, 8), 0, stream>>>(Vb, Vt);
    attn_kernel<<<dim3(SEQ / 64, BATCH * NHEADS), 256, 0, stream>>>(Qb, Kb, Vt, Yatt);
    gemm_bt<1><<<dim3(8, 64), 256, 0, stream>>>(Yatt, wprojT, b_proj, out, nullptr, nullptr,
                                                nullptr, MROWS, DMODEL, DMODEL);
}